// Round 1
// 1460.947 us; speedup vs baseline: 1.1278x; 1.1278x over previous
//
#include <hip/hip_runtime.h>

#define S_LEN 2048
#define B_SZ  2
#define E_SZ  1024
#define H_SZ  16
#define D_SZ  64

typedef __attribute__((ext_vector_type(8))) _Float16 f16x8;
typedef __attribute__((ext_vector_type(4))) _Float16 f16x4;
typedef __attribute__((ext_vector_type(4))) float    f32x4;

#define MFMA16(A,B,C) __builtin_amdgcn_mfma_f32_16x16x32_f16(A,B,C,0,0,0)

// fp32 -> f16 hi/lo split; lo pre-scaled by 2^11 to stay in f16 normal range.
// x ~= (float)h + (float)l * (1/2048).  Effective mantissa ~22 bits.
__device__ __forceinline__ void splitf(float x, _Float16& h, _Float16& l)
{
    _Float16 hh = (_Float16)x;
    h = hh;
    l = (_Float16)((x - (float)hh) * 2048.0f);
}

__device__ __forceinline__ void split_store4(float4 v, _Float16* ph, _Float16* pl)
{
    _Float16 h0,h1,h2,h3,l0,l1,l2,l3;
    splitf(v.x,h0,l0); splitf(v.y,h1,l1); splitf(v.z,h2,l2); splitf(v.w,h3,l3);
    *(f16x4*)ph = (f16x4){h0,h1,h2,h3};
    *(f16x4*)pl = (f16x4){l0,l1,l2,l3};
}

// ---------------------------------------------------------------------------
// QKV projection: C[r,n] = sum_k X[r,k]*W[n,k] + bias[n]
// Tile 64(M) x 128(N), BK=32, 256 threads = 4 waves (wave grid 1x4, wave 64x32).
// Output written as f16 hi/lo pairs. VT=0: [B,H,S,D]; VT=1: [B,H,D,S] (for V).
// ---------------------------------------------------------------------------
template<int VT>
__global__ __launch_bounds__(256, 2) void proj_qkv_mfma(
    const float* __restrict__ X,    // [S*B, E], row r = s*B + b
    const float* __restrict__ W,    // [E, E]
    const float* __restrict__ bias, // [E]
    _Float16* __restrict__ Oh, _Float16* __restrict__ Ol)
{
    __shared__ __align__(16) _Float16 sAh[64][32];
    __shared__ __align__(16) _Float16 sAl[64][32];
    __shared__ __align__(16) _Float16 sBh[128][32];
    __shared__ __align__(16) _Float16 sBl[128][32];

    const int t  = threadIdx.x;
    const int w  = t >> 6;
    const int l  = t & 63;
    const int lr = l & 15;
    const int lg = l >> 4;
    const int kb = lg * 8;
    const int m0 = blockIdx.y * 64;
    const int n0 = blockIdx.x * 128;

    const int srow = t >> 3;         // 0..31
    const int sc4  = (t & 7) * 4;    // 0,4,..,28

    f32x4 acc_h[4][2] = {};
    f32x4 acc_x[4][2] = {};

    for (int k0 = 0; k0 < E_SZ; k0 += 32) {
        #pragma unroll
        for (int i = 0; i < 2; ++i) {
            int row = srow + 32 * i;
            float4 v = *(const float4*)&X[(size_t)(m0 + row) * E_SZ + k0 + sc4];
            split_store4(v, &sAh[row][sc4], &sAl[row][sc4]);
        }
        #pragma unroll
        for (int i = 0; i < 4; ++i) {
            int row = srow + 32 * i;
            float4 v = *(const float4*)&W[(size_t)(n0 + row) * E_SZ + k0 + sc4];
            split_store4(v, &sBh[row][sc4], &sBl[row][sc4]);
        }
        __syncthreads();

        f16x8 fah[4], fal[4], fbh[2], fbl[2];
        #pragma unroll
        for (int mt = 0; mt < 4; ++mt) {
            fah[mt] = *(const f16x8*)&sAh[mt*16 + lr][kb];
            fal[mt] = *(const f16x8*)&sAl[mt*16 + lr][kb];
        }
        #pragma unroll
        for (int nt = 0; nt < 2; ++nt) {
            fbh[nt] = *(const f16x8*)&sBh[w*32 + nt*16 + lr][kb];
            fbl[nt] = *(const f16x8*)&sBl[w*32 + nt*16 + lr][kb];
        }
        #pragma unroll
        for (int mt = 0; mt < 4; ++mt)
            #pragma unroll
            for (int nt = 0; nt < 2; ++nt) {
                acc_h[mt][nt] = MFMA16(fah[mt], fbh[nt], acc_h[mt][nt]);
                acc_x[mt][nt] = MFMA16(fah[mt], fbl[nt], acc_x[mt][nt]);
                acc_x[mt][nt] = MFMA16(fal[mt], fbh[nt], acc_x[mt][nt]);
            }
        __syncthreads();
    }

    // C/D layout: col = lane&15, row = 4*(lane>>4) + reg  [HW-verified]
    #pragma unroll
    for (int nt = 0; nt < 2; ++nt) {
        int c = n0 + w*32 + nt*16 + lr;
        float bv = bias[c];
        int hh = c >> 6, d = c & 63;
        #pragma unroll
        for (int mt = 0; mt < 4; ++mt)
            #pragma unroll
            for (int j = 0; j < 4; ++j) {
                int r = m0 + mt*16 + lg*4 + j;
                int s = r >> 1, b = r & 1;     // r = s*B + b
                float v = acc_h[mt][nt][j] + acc_x[mt][nt][j] * (1.0f/2048.0f) + bv;
                _Float16 vh, vl; splitf(v, vh, vl);
                size_t idx = VT ? ((size_t)((b*H_SZ + hh)*D_SZ + d)) * S_LEN + s
                                : ((size_t)((b*H_SZ + hh)*S_LEN + s)) * D_SZ + d;
                Oh[idx] = vh; Ol[idx] = vl;
            }
    }
}

// ---------------------------------------------------------------------------
// Output projection: out[s,b,n] = sum_e ctx[b,s,e]*Wo[n,e] + bo[n], fp32 out.
// ---------------------------------------------------------------------------
__global__ __launch_bounds__(256, 2) void proj_out_mfma(
    const float* __restrict__ X,    // ctx [B*S, E], row r = b*S + s
    const float* __restrict__ W,    // [E, E]
    const float* __restrict__ bias, // [E]
    float* __restrict__ out)        // [S, B, E]
{
    __shared__ __align__(16) _Float16 sAh[64][32];
    __shared__ __align__(16) _Float16 sAl[64][32];
    __shared__ __align__(16) _Float16 sBh[128][32];
    __shared__ __align__(16) _Float16 sBl[128][32];

    const int t  = threadIdx.x;
    const int w  = t >> 6;
    const int l  = t & 63;
    const int lr = l & 15;
    const int lg = l >> 4;
    const int kb = lg * 8;
    const int m0 = blockIdx.y * 64;
    const int n0 = blockIdx.x * 128;

    const int srow = t >> 3;
    const int sc4  = (t & 7) * 4;

    f32x4 acc_h[4][2] = {};
    f32x4 acc_x[4][2] = {};

    for (int k0 = 0; k0 < E_SZ; k0 += 32) {
        #pragma unroll
        for (int i = 0; i < 2; ++i) {
            int row = srow + 32 * i;
            float4 v = *(const float4*)&X[(size_t)(m0 + row) * E_SZ + k0 + sc4];
            split_store4(v, &sAh[row][sc4], &sAl[row][sc4]);
        }
        #pragma unroll
        for (int i = 0; i < 4; ++i) {
            int row = srow + 32 * i;
            float4 v = *(const float4*)&W[(size_t)(n0 + row) * E_SZ + k0 + sc4];
            split_store4(v, &sBh[row][sc4], &sBl[row][sc4]);
        }
        __syncthreads();

        f16x8 fah[4], fal[4], fbh[2], fbl[2];
        #pragma unroll
        for (int mt = 0; mt < 4; ++mt) {
            fah[mt] = *(const f16x8*)&sAh[mt*16 + lr][kb];
            fal[mt] = *(const f16x8*)&sAl[mt*16 + lr][kb];
        }
        #pragma unroll
        for (int nt = 0; nt < 2; ++nt) {
            fbh[nt] = *(const f16x8*)&sBh[w*32 + nt*16 + lr][kb];
            fbl[nt] = *(const f16x8*)&sBl[w*32 + nt*16 + lr][kb];
        }
        #pragma unroll
        for (int mt = 0; mt < 4; ++mt)
            #pragma unroll
            for (int nt = 0; nt < 2; ++nt) {
                acc_h[mt][nt] = MFMA16(fah[mt], fbh[nt], acc_h[mt][nt]);
                acc_x[mt][nt] = MFMA16(fah[mt], fbl[nt], acc_x[mt][nt]);
                acc_x[mt][nt] = MFMA16(fal[mt], fbh[nt], acc_x[mt][nt]);
            }
        __syncthreads();
    }

    #pragma unroll
    for (int nt = 0; nt < 2; ++nt) {
        int c = n0 + w*32 + nt*16 + lr;
        float bv = bias[c];
        #pragma unroll
        for (int mt = 0; mt < 4; ++mt)
            #pragma unroll
            for (int j = 0; j < 4; ++j) {
                int r = m0 + mt*16 + lg*4 + j;
                int b = r >> 11, s = r & 2047;   // r = b*S + s
                float v = acc_h[mt][nt][j] + acc_x[mt][nt][j] * (1.0f/2048.0f) + bv;
                out[((size_t)s * B_SZ + b) * E_SZ + c] = v;
            }
    }
}

// ---------------------------------------------------------------------------
// scores[bh,q,k] = (Q[bh,q,:].K[bh,k,:]) * 0.125 + biasM[q,k]
// Tile 128x128, K=64 (2 steps of 32), 4 waves 2x2, wave 64x64.
// Q/K already in f16 hi/lo -> staging is a pure vector copy.
// ---------------------------------------------------------------------------
__global__ __launch_bounds__(256, 2) void scores_mfma(
    const _Float16* __restrict__ Qh, const _Float16* __restrict__ Ql,
    const _Float16* __restrict__ Kh, const _Float16* __restrict__ Kl,
    const float* __restrict__ biasM, float* __restrict__ attn)
{
    __shared__ __align__(16) _Float16 sQh[128][32];
    __shared__ __align__(16) _Float16 sQl[128][32];
    __shared__ __align__(16) _Float16 sKh[128][32];
    __shared__ __align__(16) _Float16 sKl[128][32];

    const int t  = threadIdx.x;
    const int w  = t >> 6;
    const int l  = t & 63;
    const int lr = l & 15;
    const int lg = l >> 4;
    const int kb = lg * 8;
    const int wm = w >> 1, wn = w & 1;
    const int kc0 = blockIdx.x * 128;
    const int q0  = blockIdx.y * 128;
    const int bh  = blockIdx.z;

    const _Float16* gQh = Qh + (size_t)(bh * S_LEN + q0)  * D_SZ;
    const _Float16* gQl = Ql + (size_t)(bh * S_LEN + q0)  * D_SZ;
    const _Float16* gKh = Kh + (size_t)(bh * S_LEN + kc0) * D_SZ;
    const _Float16* gKl = Kl + (size_t)(bh * S_LEN + kc0) * D_SZ;

    const int srow = t >> 2;         // 0..63
    const int sch  = (t & 3) * 8;    // 0,8,16,24

    f32x4 acc_h[4][4] = {};
    f32x4 acc_x[4][4] = {};

    #pragma unroll
    for (int k0 = 0; k0 < D_SZ; k0 += 32) {
        #pragma unroll
        for (int i = 0; i < 2; ++i) {
            int row = srow + 64 * i;
            *(f16x8*)&sQh[row][sch] = *(const f16x8*)&gQh[(size_t)row * D_SZ + k0 + sch];
            *(f16x8*)&sQl[row][sch] = *(const f16x8*)&gQl[(size_t)row * D_SZ + k0 + sch];
            *(f16x8*)&sKh[row][sch] = *(const f16x8*)&gKh[(size_t)row * D_SZ + k0 + sch];
            *(f16x8*)&sKl[row][sch] = *(const f16x8*)&gKl[(size_t)row * D_SZ + k0 + sch];
        }
        __syncthreads();

        f16x8 fah[4], fal[4], fbh[4], fbl[4];
        #pragma unroll
        for (int i = 0; i < 4; ++i) {
            fah[i] = *(const f16x8*)&sQh[wm*64 + i*16 + lr][kb];
            fal[i] = *(const f16x8*)&sQl[wm*64 + i*16 + lr][kb];
            fbh[i] = *(const f16x8*)&sKh[wn*64 + i*16 + lr][kb];
            fbl[i] = *(const f16x8*)&sKl[wn*64 + i*16 + lr][kb];
        }
        #pragma unroll
        for (int mt = 0; mt < 4; ++mt)
            #pragma unroll
            for (int nt = 0; nt < 4; ++nt) {
                acc_h[mt][nt] = MFMA16(fah[mt], fbh[nt], acc_h[mt][nt]);
                acc_x[mt][nt] = MFMA16(fah[mt], fbl[nt], acc_x[mt][nt]);
                acc_x[mt][nt] = MFMA16(fal[mt], fbh[nt], acc_x[mt][nt]);
            }
        __syncthreads();
    }

    const float scale = 0.125f;
    #pragma unroll
    for (int mt = 0; mt < 4; ++mt)
        #pragma unroll
        for (int j = 0; j < 4; ++j) {
            int q = q0 + wm*64 + mt*16 + lg*4 + j;
            const float* bR = biasM + (size_t)q * S_LEN;
            float* oR = attn + ((size_t)bh * S_LEN + q) * S_LEN;
            #pragma unroll
            for (int nt = 0; nt < 4; ++nt) {
                int kc = kc0 + wn*64 + nt*16 + lr;
                float v = acc_h[mt][nt][j] + acc_x[mt][nt][j] * (1.0f/2048.0f);
                oR[kc] = v * scale + bR[kc];
            }
        }
}

// in-place row softmax over last dim (2048), one block per row
__global__ __launch_bounds__(256) void softmax_kernel(float* __restrict__ attn)
{
    const size_t row = blockIdx.x;
    float* p = attn + row * S_LEN;
    const int t = threadIdx.x;

    float4 v0 = *(const float4*)&p[t * 4];
    float4 v1 = *(const float4*)&p[1024 + t * 4];
    float v[8] = {v0.x, v0.y, v0.z, v0.w, v1.x, v1.y, v1.z, v1.w};

    float m = v[0];
    #pragma unroll
    for (int i = 1; i < 8; ++i) m = fmaxf(m, v[i]);
    #pragma unroll
    for (int off = 32; off; off >>= 1) m = fmaxf(m, __shfl_xor(m, off, 64));

    __shared__ float redm[4];
    __shared__ float reds[4];
    const int wave = t >> 6, lane = t & 63;
    if (lane == 0) redm[wave] = m;
    __syncthreads();
    m = fmaxf(fmaxf(redm[0], redm[1]), fmaxf(redm[2], redm[3]));

    float sum = 0.f;
    #pragma unroll
    for (int i = 0; i < 8; ++i) { v[i] = __expf(v[i] - m); sum += v[i]; }
    #pragma unroll
    for (int off = 32; off; off >>= 1) sum += __shfl_xor(sum, off, 64);
    if (lane == 0) reds[wave] = sum;
    __syncthreads();
    sum = reds[0] + reds[1] + reds[2] + reds[3];

    const float inv = 1.0f / sum;
    float4 o0 = make_float4(v[0]*inv, v[1]*inv, v[2]*inv, v[3]*inv);
    float4 o1 = make_float4(v[4]*inv, v[5]*inv, v[6]*inv, v[7]*inv);
    *(float4*)&p[t * 4]        = o0;
    *(float4*)&p[1024 + t * 4] = o1;
}

// ---------------------------------------------------------------------------
// ctx[b,q,h*64+d] = sum_k P[bh,q,k] * V[bh,k,d]
// Tile 128(q) x 64(d), BK=32, 4 waves 2x2, wave 64x32.
// P split from fp32 at staging; V pre-stored transposed [B,H,D,S] in f16 hi/lo.
// ---------------------------------------------------------------------------
__global__ __launch_bounds__(256, 2) void context_mfma(
    const float* __restrict__ P,       // [B*H, S, S] normalized attn
    const _Float16* __restrict__ Vh,   // [B*H, D, S] transposed, hi
    const _Float16* __restrict__ Vl,   // [B*H, D, S] transposed, lo
    float* __restrict__ ctx)           // [B, S, E]
{
    __shared__ __align__(16) _Float16 sPh[128][32];
    __shared__ __align__(16) _Float16 sPl[128][32];
    __shared__ __align__(16) _Float16 sVh[64][32];
    __shared__ __align__(16) _Float16 sVl[64][32];

    const int t  = threadIdx.x;
    const int w  = t >> 6;
    const int l  = t & 63;
    const int lr = l & 15;
    const int lg = l >> 4;
    const int kb = lg * 8;
    const int wm = w >> 1, wn = w & 1;
    const int q0 = blockIdx.x * 128;
    const int bh = blockIdx.y;
    const int b = bh >> 4, hd = bh & 15;

    const float* Pb = P + (size_t)(bh * S_LEN + q0) * S_LEN;
    const _Float16* gVh = Vh + (size_t)bh * D_SZ * S_LEN;
    const _Float16* gVl = Vl + (size_t)bh * D_SZ * S_LEN;

    const int prow = t >> 3, pc4 = (t & 7) * 4;  // P staging
    const int vrow = t >> 2, vch = (t & 3) * 8;  // V staging: rows d = 0..63

    f32x4 acc_h[4][2] = {};
    f32x4 acc_x[4][2] = {};

    for (int k0 = 0; k0 < S_LEN; k0 += 32) {
        #pragma unroll
        for (int i = 0; i < 4; ++i) {
            int row = prow + 32 * i;
            float4 v = *(const float4*)&Pb[(size_t)row * S_LEN + k0 + pc4];
            split_store4(v, &sPh[row][pc4], &sPl[row][pc4]);
        }
        *(f16x8*)&sVh[vrow][vch] = *(const f16x8*)&gVh[(size_t)vrow * S_LEN + k0 + vch];
        *(f16x8*)&sVl[vrow][vch] = *(const f16x8*)&gVl[(size_t)vrow * S_LEN + k0 + vch];
        __syncthreads();

        f16x8 fah[4], fal[4], fbh[2], fbl[2];
        #pragma unroll
        for (int mt = 0; mt < 4; ++mt) {
            fah[mt] = *(const f16x8*)&sPh[wm*64 + mt*16 + lr][kb];
            fal[mt] = *(const f16x8*)&sPl[wm*64 + mt*16 + lr][kb];
        }
        #pragma unroll
        for (int nt = 0; nt < 2; ++nt) {
            fbh[nt] = *(const f16x8*)&sVh[wn*32 + nt*16 + lr][kb];
            fbl[nt] = *(const f16x8*)&sVl[wn*32 + nt*16 + lr][kb];
        }
        #pragma unroll
        for (int mt = 0; mt < 4; ++mt)
            #pragma unroll
            for (int nt = 0; nt < 2; ++nt) {
                acc_h[mt][nt] = MFMA16(fah[mt], fbh[nt], acc_h[mt][nt]);
                acc_x[mt][nt] = MFMA16(fah[mt], fbl[nt], acc_x[mt][nt]);
                acc_x[mt][nt] = MFMA16(fal[mt], fbh[nt], acc_x[mt][nt]);
            }
        __syncthreads();
    }

    #pragma unroll
    for (int mt = 0; mt < 4; ++mt)
        #pragma unroll
        for (int j = 0; j < 4; ++j) {
            int q = q0 + wm*64 + mt*16 + lg*4 + j;
            #pragma unroll
            for (int nt = 0; nt < 2; ++nt) {
                int d = wn*32 + nt*16 + lr;
                float v = acc_h[mt][nt][j] + acc_x[mt][nt][j] * (1.0f/2048.0f);
                ctx[((size_t)b * S_LEN + q) * E_SZ + hd * D_SZ + d] = v;
            }
        }
}

extern "C" void kernel_launch(void* const* d_in, const int* in_sizes, int n_in,
                              void* d_out, int out_size, void* d_ws, size_t ws_size,
                              hipStream_t stream)
{
    const float* query = (const float*)d_in[0];
    const float* key_  = (const float*)d_in[1];
    const float* value = (const float*)d_in[2];
    const float* Wq    = (const float*)d_in[3];
    const float* bq    = (const float*)d_in[4];
    const float* Wk    = (const float*)d_in[5];
    const float* bk    = (const float*)d_in[6];
    const float* Wv    = (const float*)d_in[7];
    const float* bv    = (const float*)d_in[8];
    const float* Wo    = (const float*)d_in[9];
    const float* bo    = (const float*)d_in[10];
    const float* biasM = (const float*)d_in[11];

    float* out  = (float*)d_out;                                  // [S,B,E]
    float* attn = (float*)d_out + (size_t)S_LEN * B_SZ * E_SZ;    // [B,H,S,S]

    const size_t qsz = (size_t)B_SZ * H_SZ * S_LEN * D_SZ;        // 4M elems
    _Float16* ws16 = (_Float16*)d_ws;
    _Float16* Qh = ws16;                  // 8 MB each
    _Float16* Ql = ws16 + qsz;
    _Float16* Kh = ws16 + 2 * qsz;
    _Float16* Kl = ws16 + 3 * qsz;
    _Float16* Vh = ws16 + 4 * qsz;        // transposed [B,H,D,S]
    _Float16* Vl = ws16 + 5 * qsz;
    float* ctx = (float*)(ws16 + 6 * qsz);   // [B,S,E] fp32, 16 MB; total 64 MB

    dim3 gp(E_SZ / 128, (S_LEN * B_SZ) / 64);   // (8, 64) = 512 blocks
    proj_qkv_mfma<0><<<gp, dim3(256), 0, stream>>>(query, Wq, bq, Qh, Ql);
    proj_qkv_mfma<0><<<gp, dim3(256), 0, stream>>>(key_,  Wk, bk, Kh, Kl);
    proj_qkv_mfma<1><<<gp, dim3(256), 0, stream>>>(value, Wv, bv, Vh, Vl);

    dim3 gsc(S_LEN / 128, S_LEN / 128, B_SZ * H_SZ);   // (16,16,32)
    scores_mfma<<<gsc, dim3(256), 0, stream>>>(Qh, Ql, Kh, Kl, biasM, attn);

    softmax_kernel<<<dim3(B_SZ * H_SZ * S_LEN), dim3(256), 0, stream>>>(attn);

    dim3 gctx(S_LEN / 128, B_SZ * H_SZ);               // (16,32)
    context_mfma<<<gctx, dim3(256), 0, stream>>>(attn, Vh, Vl, ctx);

    proj_out_mfma<<<gp, dim3(256), 0, stream>>>(ctx, Wo, bo, out);
}

// Round 2
// 1252.927 us; speedup vs baseline: 1.3151x; 1.1660x over previous
//
#include <hip/hip_runtime.h>

#define S_LEN 2048
#define B_SZ  2
#define E_SZ  1024
#define H_SZ  16
#define D_SZ  64

typedef __attribute__((ext_vector_type(8))) _Float16 f16x8;
typedef __attribute__((ext_vector_type(4))) _Float16 f16x4;
typedef __attribute__((ext_vector_type(4))) float    f32x4;

#define MFMA16(A,B,C) __builtin_amdgcn_mfma_f32_16x16x32_f16(A,B,C,0,0,0)
// LDS f16 row stride 40 elems = 80 B: 16B-aligned rows, gcd(20,32)=4 -> max
// 2-way bank aliasing on ds_read_b128 quarter-phases (2-way is free, m136).
#define LPAD 40

// fp32 -> f16 hi/lo split; lo pre-scaled by 2^11. x ~= h + l*(1/2048), ~22-bit.
__device__ __forceinline__ void splitf(float x, _Float16& h, _Float16& l)
{
    _Float16 hh = (_Float16)x;
    h = hh;
    l = (_Float16)((x - (float)hh) * 2048.0f);
}

__device__ __forceinline__ void split_store4(float4 v, _Float16* ph, _Float16* pl)
{
    _Float16 h0,h1,h2,h3,l0,l1,l2,l3;
    splitf(v.x,h0,l0); splitf(v.y,h1,l1); splitf(v.z,h2,l2); splitf(v.w,h3,l3);
    *(f16x4*)ph = (f16x4){h0,h1,h2,h3};
    *(f16x4*)pl = (f16x4){l0,l1,l2,l3};
}

// ---------------------------------------------------------------------------
// One-shot pre-split of q,k,v (4M floats each) and Wq,Wk,Wv (1M each) into
// f16 hi/lo scratch. 2048 floats per block -> 7680 blocks. Memory-bound.
// ---------------------------------------------------------------------------
__global__ __launch_bounds__(256) void split_all(
    const float* __restrict__ q, const float* __restrict__ k, const float* __restrict__ v,
    const float* __restrict__ wq, const float* __restrict__ wk, const float* __restrict__ wv,
    _Float16* __restrict__ H)
{
    const size_t M4 = 4194304, M1 = 1048576;
    int blk = blockIdx.x;
    const float* s; _Float16 *ph, *pl; size_t lb;
    if      (blk < 2048) { s=q;  lb=blk;      ph=H;            pl=H+M4; }
    else if (blk < 4096) { s=k;  lb=blk-2048; ph=H+2*M4;       pl=H+3*M4; }
    else if (blk < 6144) { s=v;  lb=blk-4096; ph=H+4*M4;       pl=H+5*M4; }
    else if (blk < 6656) { s=wq; lb=blk-6144; ph=H+6*M4;       pl=H+6*M4+M1; }
    else if (blk < 7168) { s=wk; lb=blk-6656; ph=H+6*M4+2*M1;  pl=H+6*M4+3*M1; }
    else                 { s=wv; lb=blk-7168; ph=H+6*M4+4*M1;  pl=H+6*M4+5*M1; }
    size_t base = lb * 2048 + (size_t)threadIdx.x * 8;
    float4 a = *(const float4*)&s[base];
    float4 b = *(const float4*)&s[base + 4];
    _Float16 h0,h1,h2,h3,h4,h5,h6,h7, l0,l1,l2,l3,l4,l5,l6,l7;
    splitf(a.x,h0,l0); splitf(a.y,h1,l1); splitf(a.z,h2,l2); splitf(a.w,h3,l3);
    splitf(b.x,h4,l4); splitf(b.y,h5,l5); splitf(b.z,h6,l6); splitf(b.w,h7,l7);
    *(f16x8*)&ph[base] = (f16x8){h0,h1,h2,h3,h4,h5,h6,h7};
    *(f16x8*)&pl[base] = (f16x8){l0,l1,l2,l3,l4,l5,l6,l7};
}

// ---------------------------------------------------------------------------
// QKV projection from pre-split operands: C[r,n] = sum_k A[r,k]*B[n,k] + bias[n]
// Tile 128x128, BK=32, 4 waves 2x2 (wave 64x64). Pure-copy staging.
// VT=0: out [B,H,S,D]; VT=1: out [B,H,D,S] (V, transposed for context).
// ---------------------------------------------------------------------------
template<int VT>
__global__ __launch_bounds__(256, 2) void proj_f16(
    const _Float16* __restrict__ Ah, const _Float16* __restrict__ Al, // [4096][1024], r = s*B+b
    const _Float16* __restrict__ Bh, const _Float16* __restrict__ Bl, // [1024][1024]
    const float* __restrict__ bias,
    _Float16* __restrict__ Oh, _Float16* __restrict__ Ol)
{
    __shared__ __align__(16) _Float16 sAh[128][LPAD], sAl[128][LPAD];
    __shared__ __align__(16) _Float16 sBh[128][LPAD], sBl[128][LPAD];
    const int t = threadIdx.x, w = t >> 6, l = t & 63;
    const int lr = l & 15, lg = l >> 4, kb = lg * 8;
    const int wm = w >> 1, wn = w & 1;
    const int m0 = blockIdx.y * 128, n0 = blockIdx.x * 128;
    const int crow = t >> 2, ccol = (t & 3) * 8;

    f32x4 acc_h[4][4] = {}, acc_x[4][4] = {};

    for (int k0 = 0; k0 < E_SZ; k0 += 32) {
        #pragma unroll
        for (int i = 0; i < 2; ++i) {
            int row = crow + 64 * i;
            *(f16x8*)&sAh[row][ccol] = *(const f16x8*)&Ah[(size_t)(m0+row)*E_SZ + k0 + ccol];
            *(f16x8*)&sAl[row][ccol] = *(const f16x8*)&Al[(size_t)(m0+row)*E_SZ + k0 + ccol];
            *(f16x8*)&sBh[row][ccol] = *(const f16x8*)&Bh[(size_t)(n0+row)*E_SZ + k0 + ccol];
            *(f16x8*)&sBl[row][ccol] = *(const f16x8*)&Bl[(size_t)(n0+row)*E_SZ + k0 + ccol];
        }
        __syncthreads();
        f16x8 fah[4], fal[4], fbh[4], fbl[4];
        #pragma unroll
        for (int i = 0; i < 4; ++i) {
            fah[i] = *(const f16x8*)&sAh[wm*64 + i*16 + lr][kb];
            fal[i] = *(const f16x8*)&sAl[wm*64 + i*16 + lr][kb];
            fbh[i] = *(const f16x8*)&sBh[wn*64 + i*16 + lr][kb];
            fbl[i] = *(const f16x8*)&sBl[wn*64 + i*16 + lr][kb];
        }
        #pragma unroll
        for (int mt = 0; mt < 4; ++mt)
            #pragma unroll
            for (int nt = 0; nt < 4; ++nt) {
                acc_h[mt][nt] = MFMA16(fah[mt], fbh[nt], acc_h[mt][nt]);
                acc_x[mt][nt] = MFMA16(fah[mt], fbl[nt], acc_x[mt][nt]);
                acc_x[mt][nt] = MFMA16(fal[mt], fbh[nt], acc_x[mt][nt]);
            }
        __syncthreads();
    }

    // C/D layout: col = lane&15, row = 4*(lane>>4) + reg  [HW-verified]
    #pragma unroll
    for (int nt = 0; nt < 4; ++nt) {
        int c = n0 + wn*64 + nt*16 + lr;
        float bv = bias[c];
        int hh = c >> 6, d = c & 63;
        #pragma unroll
        for (int mt = 0; mt < 4; ++mt)
            #pragma unroll
            for (int j = 0; j < 4; ++j) {
                int r = m0 + wm*64 + mt*16 + lg*4 + j;
                int s = r >> 1, b = r & 1;       // r = s*B + b
                float vv = acc_h[mt][nt][j] + acc_x[mt][nt][j] * (1.0f/2048.0f) + bv;
                _Float16 vh, vl; splitf(vv, vh, vl);
                size_t idx = VT ? ((size_t)((b*H_SZ + hh)*D_SZ + d)) * S_LEN + s
                                : ((size_t)((b*H_SZ + hh)*S_LEN + s)) * D_SZ + d;
                Oh[idx] = vh; Ol[idx] = vl;
            }
    }
}

// ---------------------------------------------------------------------------
// Output projection: out[s,b,n] = sum_e ctx[b,s,e]*Wo[n,e] + bo[n], fp32 out.
// A = ctx pre-split f16 (pure copy); B = Wo fp32, split in-loop.
// ---------------------------------------------------------------------------
__global__ __launch_bounds__(256, 2) void proj_out_f16(
    const _Float16* __restrict__ Ah, const _Float16* __restrict__ Al, // [4096][1024], r = b*S+s
    const float* __restrict__ W,     // [1024][1024] fp32
    const float* __restrict__ bias,
    float* __restrict__ out)         // [S,B,E]
{
    __shared__ __align__(16) _Float16 sAh[128][LPAD], sAl[128][LPAD];
    __shared__ __align__(16) _Float16 sBh[128][LPAD], sBl[128][LPAD];
    const int t = threadIdx.x, w = t >> 6, l = t & 63;
    const int lr = l & 15, lg = l >> 4, kb = lg * 8;
    const int wm = w >> 1, wn = w & 1;
    const int m0 = blockIdx.y * 128, n0 = blockIdx.x * 128;
    const int crow = t >> 2, ccol = (t & 3) * 8;   // A copy
    const int brow = t >> 3, bc4  = (t & 7) * 4;   // W split

    f32x4 acc_h[4][4] = {}, acc_x[4][4] = {};

    for (int k0 = 0; k0 < E_SZ; k0 += 32) {
        #pragma unroll
        for (int i = 0; i < 2; ++i) {
            int row = crow + 64 * i;
            *(f16x8*)&sAh[row][ccol] = *(const f16x8*)&Ah[(size_t)(m0+row)*E_SZ + k0 + ccol];
            *(f16x8*)&sAl[row][ccol] = *(const f16x8*)&Al[(size_t)(m0+row)*E_SZ + k0 + ccol];
        }
        #pragma unroll
        for (int i = 0; i < 4; ++i) {
            int row = brow + 32 * i;
            float4 v = *(const float4*)&W[(size_t)(n0+row)*E_SZ + k0 + bc4];
            split_store4(v, &sBh[row][bc4], &sBl[row][bc4]);
        }
        __syncthreads();
        f16x8 fah[4], fal[4], fbh[4], fbl[4];
        #pragma unroll
        for (int i = 0; i < 4; ++i) {
            fah[i] = *(const f16x8*)&sAh[wm*64 + i*16 + lr][kb];
            fal[i] = *(const f16x8*)&sAl[wm*64 + i*16 + lr][kb];
            fbh[i] = *(const f16x8*)&sBh[wn*64 + i*16 + lr][kb];
            fbl[i] = *(const f16x8*)&sBl[wn*64 + i*16 + lr][kb];
        }
        #pragma unroll
        for (int mt = 0; mt < 4; ++mt)
            #pragma unroll
            for (int nt = 0; nt < 4; ++nt) {
                acc_h[mt][nt] = MFMA16(fah[mt], fbh[nt], acc_h[mt][nt]);
                acc_x[mt][nt] = MFMA16(fah[mt], fbl[nt], acc_x[mt][nt]);
                acc_x[mt][nt] = MFMA16(fal[mt], fbh[nt], acc_x[mt][nt]);
            }
        __syncthreads();
    }

    #pragma unroll
    for (int nt = 0; nt < 4; ++nt) {
        int c = n0 + wn*64 + nt*16 + lr;
        float bv = bias[c];
        #pragma unroll
        for (int mt = 0; mt < 4; ++mt)
            #pragma unroll
            for (int j = 0; j < 4; ++j) {
                int r = m0 + wm*64 + mt*16 + lg*4 + j;
                int b = r >> 11, s = r & 2047;   // r = b*S + s
                float vv = acc_h[mt][nt][j] + acc_x[mt][nt][j] * (1.0f/2048.0f) + bv;
                out[((size_t)s * B_SZ + b) * E_SZ + c] = vv;
            }
    }
}

// ---------------------------------------------------------------------------
// scores[bh,q,k] = (Q[bh,q,:].K[bh,k,:]) * 0.125 + biasM[q,k]
// Tile 128x128, 4 waves 2x2, D=64 in 2 K-steps. Pure-copy staging.
// ---------------------------------------------------------------------------
__global__ __launch_bounds__(256, 2) void scores_mfma(
    const _Float16* __restrict__ Qh, const _Float16* __restrict__ Ql,
    const _Float16* __restrict__ Kh, const _Float16* __restrict__ Kl,
    const float* __restrict__ biasM, float* __restrict__ attn)
{
    __shared__ __align__(16) _Float16 sQh[128][LPAD], sQl[128][LPAD];
    __shared__ __align__(16) _Float16 sKh[128][LPAD], sKl[128][LPAD];
    const int t = threadIdx.x, w = t >> 6, l = t & 63;
    const int lr = l & 15, lg = l >> 4, kb = lg * 8;
    const int wm = w >> 1, wn = w & 1;
    const int kc0 = blockIdx.x * 128, q0 = blockIdx.y * 128;
    const int bh = blockIdx.z;

    const _Float16* gQh = Qh + (size_t)(bh * S_LEN + q0)  * D_SZ;
    const _Float16* gQl = Ql + (size_t)(bh * S_LEN + q0)  * D_SZ;
    const _Float16* gKh = Kh + (size_t)(bh * S_LEN + kc0) * D_SZ;
    const _Float16* gKl = Kl + (size_t)(bh * S_LEN + kc0) * D_SZ;

    const int srow = t >> 2, sch = (t & 3) * 8;

    f32x4 acc_h[4][4] = {}, acc_x[4][4] = {};

    #pragma unroll
    for (int k0 = 0; k0 < D_SZ; k0 += 32) {
        #pragma unroll
        for (int i = 0; i < 2; ++i) {
            int row = srow + 64 * i;
            *(f16x8*)&sQh[row][sch] = *(const f16x8*)&gQh[(size_t)row * D_SZ + k0 + sch];
            *(f16x8*)&sQl[row][sch] = *(const f16x8*)&gQl[(size_t)row * D_SZ + k0 + sch];
            *(f16x8*)&sKh[row][sch] = *(const f16x8*)&gKh[(size_t)row * D_SZ + k0 + sch];
            *(f16x8*)&sKl[row][sch] = *(const f16x8*)&gKl[(size_t)row * D_SZ + k0 + sch];
        }
        __syncthreads();
        f16x8 fah[4], fal[4], fbh[4], fbl[4];
        #pragma unroll
        for (int i = 0; i < 4; ++i) {
            fah[i] = *(const f16x8*)&sQh[wm*64 + i*16 + lr][kb];
            fal[i] = *(const f16x8*)&sQl[wm*64 + i*16 + lr][kb];
            fbh[i] = *(const f16x8*)&sKh[wn*64 + i*16 + lr][kb];
            fbl[i] = *(const f16x8*)&sKl[wn*64 + i*16 + lr][kb];
        }
        #pragma unroll
        for (int mt = 0; mt < 4; ++mt)
            #pragma unroll
            for (int nt = 0; nt < 4; ++nt) {
                acc_h[mt][nt] = MFMA16(fah[mt], fbh[nt], acc_h[mt][nt]);
                acc_x[mt][nt] = MFMA16(fah[mt], fbl[nt], acc_x[mt][nt]);
                acc_x[mt][nt] = MFMA16(fal[mt], fbh[nt], acc_x[mt][nt]);
            }
        __syncthreads();
    }

    const float scale = 0.125f;
    #pragma unroll
    for (int mt = 0; mt < 4; ++mt)
        #pragma unroll
        for (int j = 0; j < 4; ++j) {
            int q = q0 + wm*64 + mt*16 + lg*4 + j;
            const float* bR = biasM + (size_t)q * S_LEN;
            float* oR = attn + ((size_t)bh * S_LEN + q) * S_LEN;
            #pragma unroll
            for (int nt = 0; nt < 4; ++nt) {
                int kc = kc0 + wn*64 + nt*16 + lr;
                float v = acc_h[mt][nt][j] + acc_x[mt][nt][j] * (1.0f/2048.0f);
                oR[kc] = v * scale + bR[kc];
            }
        }
}

// in-place row softmax over last dim (2048), one block per row
__global__ __launch_bounds__(256) void softmax_kernel(float* __restrict__ attn)
{
    const size_t row = blockIdx.x;
    float* p = attn + row * S_LEN;
    const int t = threadIdx.x;

    float4 v0 = *(const float4*)&p[t * 4];
    float4 v1 = *(const float4*)&p[1024 + t * 4];
    float v[8] = {v0.x, v0.y, v0.z, v0.w, v1.x, v1.y, v1.z, v1.w};

    float m = v[0];
    #pragma unroll
    for (int i = 1; i < 8; ++i) m = fmaxf(m, v[i]);
    #pragma unroll
    for (int off = 32; off; off >>= 1) m = fmaxf(m, __shfl_xor(m, off, 64));

    __shared__ float redm[4];
    __shared__ float reds[4];
    const int wave = t >> 6, lane = t & 63;
    if (lane == 0) redm[wave] = m;
    __syncthreads();
    m = fmaxf(fmaxf(redm[0], redm[1]), fmaxf(redm[2], redm[3]));

    float sum = 0.f;
    #pragma unroll
    for (int i = 0; i < 8; ++i) { v[i] = __expf(v[i] - m); sum += v[i]; }
    #pragma unroll
    for (int off = 32; off; off >>= 1) sum += __shfl_xor(sum, off, 64);
    if (lane == 0) reds[wave] = sum;
    __syncthreads();
    sum = reds[0] + reds[1] + reds[2] + reds[3];

    const float inv = 1.0f / sum;
    float4 o0 = make_float4(v[0]*inv, v[1]*inv, v[2]*inv, v[3]*inv);
    float4 o1 = make_float4(v[4]*inv, v[5]*inv, v[6]*inv, v[7]*inv);
    *(float4*)&p[t * 4]        = o0;
    *(float4*)&p[1024 + t * 4] = o1;
}

// ---------------------------------------------------------------------------
// ctx[b,q,h*64+d] = sum_k P[bh,q,k] * V[bh,k,d]; ctx written as f16 hi/lo.
// P: hi-only cvt in-loop (P in [0,1], sum 1 -> lo term negligible).
// V: pre-stored transposed [B,H,D,S] f16 hi/lo. Tile 128(q) x 64(d), BK=32.
// ---------------------------------------------------------------------------
__global__ __launch_bounds__(256, 2) void context_mfma(
    const float* __restrict__ P,
    const _Float16* __restrict__ Vh, const _Float16* __restrict__ Vl,
    _Float16* __restrict__ Ch, _Float16* __restrict__ Cl)   // ctx [B*S,E] split
{
    __shared__ __align__(16) _Float16 sPh[128][LPAD];
    __shared__ __align__(16) _Float16 sVh[64][LPAD], sVl[64][LPAD];
    const int t = threadIdx.x, w = t >> 6, l = t & 63;
    const int lr = l & 15, lg = l >> 4, kb = lg * 8;
    const int wm = w >> 1, wn = w & 1;
    const int q0 = blockIdx.x * 128;
    const int bh = blockIdx.y;
    const int b = bh >> 4, hd = bh & 15;

    const float* Pb = P + (size_t)(bh * S_LEN + q0) * S_LEN;
    const _Float16* gVh = Vh + (size_t)bh * D_SZ * S_LEN;
    const _Float16* gVl = Vl + (size_t)bh * D_SZ * S_LEN;

    const int prow = t >> 3, pc4 = (t & 7) * 4;
    const int vrow = t >> 2, vch = (t & 3) * 8;

    f32x4 acc_h[4][2] = {}, acc_x[4][2] = {};

    for (int k0 = 0; k0 < S_LEN; k0 += 32) {
        #pragma unroll
        for (int i = 0; i < 4; ++i) {
            int row = prow + 32 * i;
            float4 v = *(const float4*)&Pb[(size_t)row * S_LEN + k0 + pc4];
            _Float16 p0 = (_Float16)v.x, p1 = (_Float16)v.y,
                     p2 = (_Float16)v.z, p3 = (_Float16)v.w;
            *(f16x4*)&sPh[row][pc4] = (f16x4){p0,p1,p2,p3};
        }
        *(f16x8*)&sVh[vrow][vch] = *(const f16x8*)&gVh[(size_t)vrow * S_LEN + k0 + vch];
        *(f16x8*)&sVl[vrow][vch] = *(const f16x8*)&gVl[(size_t)vrow * S_LEN + k0 + vch];
        __syncthreads();
        f16x8 pa[4], vbh[2], vbl[2];
        #pragma unroll
        for (int mt = 0; mt < 4; ++mt)
            pa[mt] = *(const f16x8*)&sPh[wm*64 + mt*16 + lr][kb];
        #pragma unroll
        for (int nt = 0; nt < 2; ++nt) {
            vbh[nt] = *(const f16x8*)&sVh[wn*32 + nt*16 + lr][kb];
            vbl[nt] = *(const f16x8*)&sVl[wn*32 + nt*16 + lr][kb];
        }
        #pragma unroll
        for (int mt = 0; mt < 4; ++mt)
            #pragma unroll
            for (int nt = 0; nt < 2; ++nt) {
                acc_h[mt][nt] = MFMA16(pa[mt], vbh[nt], acc_h[mt][nt]);
                acc_x[mt][nt] = MFMA16(pa[mt], vbl[nt], acc_x[mt][nt]);
            }
        __syncthreads();
    }

    #pragma unroll
    for (int mt = 0; mt < 4; ++mt)
        #pragma unroll
        for (int j = 0; j < 4; ++j) {
            int q = q0 + wm*64 + mt*16 + lg*4 + j;
            #pragma unroll
            for (int nt = 0; nt < 2; ++nt) {
                int d = wn*32 + nt*16 + lr;
                float vv = acc_h[mt][nt][j] + acc_x[mt][nt][j] * (1.0f/2048.0f);
                _Float16 vh, vl; splitf(vv, vh, vl);
                size_t idx = ((size_t)b * S_LEN + q) * E_SZ + hd * D_SZ + d;
                Ch[idx] = vh; Cl[idx] = vl;
            }
        }
}

extern "C" void kernel_launch(void* const* d_in, const int* in_sizes, int n_in,
                              void* d_out, int out_size, void* d_ws, size_t ws_size,
                              hipStream_t stream)
{
    const float* query = (const float*)d_in[0];
    const float* key_  = (const float*)d_in[1];
    const float* value = (const float*)d_in[2];
    const float* Wq    = (const float*)d_in[3];
    const float* bq    = (const float*)d_in[4];
    const float* Wk    = (const float*)d_in[5];
    const float* bk    = (const float*)d_in[6];
    const float* Wv    = (const float*)d_in[7];
    const float* bv    = (const float*)d_in[8];
    const float* Wo    = (const float*)d_in[9];
    const float* bo    = (const float*)d_in[10];
    const float* biasM = (const float*)d_in[11];

    float* out  = (float*)d_out;                                  // [S,B,E]
    float* attn = (float*)d_out + (size_t)S_LEN * B_SZ * E_SZ;    // [B,H,S,S]

    // Pre-split scratch lives in the attn output region (537 MB): consumed by
    // the projection kernels BEFORE scores_mfma overwrites attn. Stream order
    // guarantees safety. 60 MB used.
    _Float16* scratch = (_Float16*)attn;
    const size_t M4 = 4194304, M1 = 1048576;
    _Float16* Xq_h = scratch;            _Float16* Xq_l = scratch + M4;
    _Float16* Xk_h = scratch + 2*M4;     _Float16* Xk_l = scratch + 3*M4;
    _Float16* Xv_h = scratch + 4*M4;     _Float16* Xv_l = scratch + 5*M4;
    _Float16* Wq_h = scratch + 6*M4;          _Float16* Wq_l = Wq_h + M1;
    _Float16* Wk_h = scratch + 6*M4 + 2*M1;   _Float16* Wk_l = Wk_h + M1;
    _Float16* Wv_h = scratch + 6*M4 + 4*M1;   _Float16* Wv_l = Wv_h + M1;

    // Workspace (64 MB): Q/K/V f16 hi/lo + ctx f16 hi/lo
    const size_t qsz = (size_t)B_SZ * H_SZ * S_LEN * D_SZ;        // 4M elems
    _Float16* ws16 = (_Float16*)d_ws;
    _Float16* Qh = ws16;            _Float16* Ql = ws16 + qsz;
    _Float16* Kh = ws16 + 2*qsz;    _Float16* Kl = ws16 + 3*qsz;
    _Float16* Vh = ws16 + 4*qsz;    _Float16* Vl = ws16 + 5*qsz;  // [B,H,D,S]
    _Float16* Ch = ws16 + 6*qsz;    _Float16* Cl = ws16 + 7*qsz;  // ctx [B*S,E]

    split_all<<<dim3(7680), dim3(256), 0, stream>>>(query, key_, value, Wq, Wk, Wv, scratch);

    dim3 gp(E_SZ / 128, (S_LEN * B_SZ) / 128);   // (8, 32) = 256 blocks
    proj_f16<0><<<gp, dim3(256), 0, stream>>>(Xq_h, Xq_l, Wq_h, Wq_l, bq, Qh, Ql);
    proj_f16<0><<<gp, dim3(256), 0, stream>>>(Xk_h, Xk_l, Wk_h, Wk_l, bk, Kh, Kl);
    proj_f16<1><<<gp, dim3(256), 0, stream>>>(Xv_h, Xv_l, Wv_h, Wv_l, bv, Vh, Vl);

    dim3 gsc(S_LEN / 128, S_LEN / 128, B_SZ * H_SZ);   // (16,16,32)
    scores_mfma<<<gsc, dim3(256), 0, stream>>>(Qh, Ql, Kh, Kl, biasM, attn);

    softmax_kernel<<<dim3(B_SZ * H_SZ * S_LEN), dim3(256), 0, stream>>>(attn);

    dim3 gctx(S_LEN / 128, B_SZ * H_SZ);               // (16,32)
    context_mfma<<<gctx, dim3(256), 0, stream>>>(attn, Vh, Vl, Ch, Cl);

    proj_out_f16<<<gp, dim3(256), 0, stream>>>(Ch, Cl, Wo, bo, out);
}